// Round 1
// baseline (9631.480 us; speedup 1.0000x reference)
//
#include <hip/hip_runtime.h>
#include <math.h>

#define B 128
#define T 1998
#define H 256
#define U 256
#define KTOP 1332
#define BT (B*T)

// ---------------- workspace layout (float elements) ----------------
// Region A (reused):
//   phase 1: conv partials [4][B][T]            = 4*BT
//   phase 2: score[BT], sig[BT], den(pad 2048), ctx_part[8][B][H]
#define WS_CONVPART 0
#define WS_SCORE    0
#define WS_SIG      (BT)
#define WS_DEN      (2*BT)
#define WS_CTXPART  (2*BT + 2048)
#define WS_CONVO    (4*BT)
#define WS_QPROJ    (5*BT)

// ---------------- q_proj = query @ W2^T + b2 ----------------
__global__ void qproj_kernel(const float* __restrict__ query,
                             const float* __restrict__ W2w,
                             const float* __restrict__ W2b,
                             float* __restrict__ qproj) {
    __shared__ __align__(16) float qs[H];
    int b = blockIdx.x;
    int u = threadIdx.x;
    qs[u] = query[b*H + u];
    __syncthreads();
    const float4* w  = (const float4*)(W2w + u*H);
    const float4* q4 = (const float4*)qs;
    float acc = 0.f;
    #pragma unroll 8
    for (int i = 0; i < H/4; ++i) {
        float4 wv = w[i]; float4 qv = q4[i];
        acc += wv.x*qv.x + wv.y*qv.y + wv.z*qv.z + wv.w*qv.w;
    }
    qproj[b*U + u] = acc + W2b[u];
}

// ---------------- conv: part[c][b][t] = sum_{i in chunk c} prev[b,i]*conv_w[t,i,3] ----------------
#define CT 32
#define CCHUNK 500
__global__ __launch_bounds__(256)
void conv_kernel(const float* __restrict__ prev,
                 const float* __restrict__ convw,
                 float* __restrict__ part) {
    __shared__ __align__(16) float W3s[CT*68];   // pad 68: odd #16B-groups per row
    __shared__ __align__(16) float Ps[B*68];
    int t0 = blockIdx.x * CT;
    int i_begin = blockIdx.y * CCHUNK;
    int i_end = min(T, i_begin + CCHUNK);
    int tid = threadIdx.x;
    int tx = tid & 7;          // -> t = t0 + tx + 8r  (lane-stride 1 in t)
    int ty = tid >> 3;         // -> b = ty + 32j      (lane-stride 1 in b)
    float acc[4][4] = {};
    for (int i0 = i_begin; i0 < i_end; i0 += 64) {
        int ni = i_end - i0; if (ni > 64) ni = 64;
        #pragma unroll
        for (int r = 0; r < 8; ++r) {              // stage W3 32x64 (strided x7 gather)
            int idx = tid + 256*r;
            int tl = idx >> 6, il = idx & 63;
            int t = t0 + tl;
            float v = 0.f;
            if (il < ni && t < T) v = convw[((long)t*T + (i0+il))*7 + 3];
            W3s[tl*68 + il] = v;
        }
        #pragma unroll
        for (int r = 0; r < 16; ++r) {             // stage P 128x64 via float2
            int idx = tid + 256*r;
            int bl = idx >> 5, i2 = idx & 31;
            int il = i2*2;
            float vx = 0.f, vy = 0.f;
            if (il < ni) {
                if (il + 1 < ni) {
                    float2 v = *(const float2*)(prev + bl*T + i0 + il);
                    vx = v.x; vy = v.y;
                } else vx = prev[bl*T + i0 + il];
            }
            Ps[bl*68 + il] = vx; Ps[bl*68 + il + 1] = vy;
        }
        __syncthreads();
        const float4* W3f = (const float4*)W3s;
        const float4* Pf  = (const float4*)Ps;
        #pragma unroll
        for (int i4 = 0; i4 < 16; ++i4) {
            float4 w4[4], p4[4];
            #pragma unroll
            for (int r = 0; r < 4; ++r) w4[r] = W3f[(tx + 8*r)*17 + i4];
            #pragma unroll
            for (int j = 0; j < 4; ++j) p4[j] = Pf[(ty + 32*j)*17 + i4];
            #pragma unroll
            for (int r = 0; r < 4; ++r)
                #pragma unroll
                for (int j = 0; j < 4; ++j)
                    acc[r][j] += w4[r].x*p4[j].x + w4[r].y*p4[j].y
                               + w4[r].z*p4[j].z + w4[r].w*p4[j].w;
        }
        __syncthreads();
    }
    int cb = blockIdx.y;
    #pragma unroll
    for (int r = 0; r < 4; ++r) {
        int t = t0 + tx + 8*r;
        if (t < T)
            #pragma unroll
            for (int j = 0; j < 4; ++j)
                part[cb*BT + (ty + 32*j)*T + t] = acc[r][j];
    }
}

__global__ void conv_reduce(const float* __restrict__ part, float* __restrict__ convo) {
    int i = blockIdx.x*256 + threadIdx.x;
    if (i < BT) convo[i] = (part[i] + part[BT+i]) + (part[2*BT+i] + part[3*BT+i]);
}

// ---------------- fused score: V.tanh(values@W1^T + b1 + qproj + convo*lp) + Vb ----------------
__global__ __launch_bounds__(256, 2)
void score_kernel(const float* __restrict__ values, const float* __restrict__ W1w,
                  const float* __restrict__ W1b, const float* __restrict__ Vw,
                  const float* __restrict__ Vb, const float* __restrict__ lp,
                  const float* __restrict__ qproj, const float* __restrict__ convo,
                  float* __restrict__ score) {
    __shared__ __align__(16) float Vs[64*36];     // stride 36: 9 (odd) 16B-groups/row
    __shared__ __align__(16) float W1s[256*36];
    __shared__ float qpS[U], bS[U], vwS[U], lpS[U];
    int b  = blockIdx.y;
    int t0 = blockIdx.x * 64;
    int tid = threadIdx.x;
    int tx = tid & 15;         // -> u = tx + 16j (lane-stride 1 => conflict-free b128)
    int ty = tid >> 4;         // -> t_local = ty + 16r
    qpS[tid] = qproj[b*U + tid];
    bS[tid]  = W1b[tid];
    vwS[tid] = Vw[tid];
    lpS[tid] = lp[tid];
    float acc[4][16] = {};
    const float4* Vsf = (const float4*)Vs;
    const float4* Wsf = (const float4*)W1s;
    for (int k0 = 0; k0 < H; k0 += 32) {
        __syncthreads();
        #pragma unroll
        for (int r = 0; r < 8; ++r) {              // stage W1 256x32
            int idx = tid + 256*r;
            int u = idx >> 3, f4 = idx & 7;
            float4 v = *(const float4*)(W1w + u*H + k0 + f4*4);
            *(float4*)(W1s + u*36 + f4*4) = v;
        }
        #pragma unroll
        for (int r = 0; r < 2; ++r) {              // stage values 64x32
            int idx = tid + 256*r;
            int row = idx >> 3, f4 = idx & 7;
            int t = t0 + row;
            float4 v = make_float4(0.f,0.f,0.f,0.f);
            if (t < T) v = *(const float4*)(values + ((long)b*T + t)*H + k0 + f4*4);
            *(float4*)(Vs + row*36 + f4*4) = v;
        }
        __syncthreads();
        #pragma unroll
        for (int k4 = 0; k4 < 8; ++k4) {
            float4 v4[4];
            #pragma unroll
            for (int r = 0; r < 4; ++r) v4[r] = Vsf[(ty + 16*r)*9 + k4];
            #pragma unroll
            for (int j = 0; j < 16; ++j) {
                float4 w4 = Wsf[(tx + 16*j)*9 + k4];
                #pragma unroll
                for (int r = 0; r < 4; ++r)
                    acc[r][j] += v4[r].x*w4.x + v4[r].y*w4.y + v4[r].z*w4.z + v4[r].w*w4.w;
            }
        }
    }
    float vb = Vb[0];
    #pragma unroll
    for (int r = 0; r < 4; ++r) {
        int t = t0 + ty + 16*r;
        float c = (t < T) ? convo[b*T + t] : 0.f;
        float part = 0.f;
        #pragma unroll
        for (int j = 0; j < 16; ++j) {
            int u = tx + 16*j;
            float s = acc[r][j] + bS[u] + qpS[u] + c*lpS[u];
            part += vwS[u] * tanhf(s);
        }
        part += __shfl_xor(part, 1);
        part += __shfl_xor(part, 2);
        part += __shfl_xor(part, 4);
        part += __shfl_xor(part, 8);
        if (tx == 0 && t < T) score[b*T + t] = part + vb;
    }
}

// ---------------- per-row exact top-K mask (radix select 11/11/10) + sigmoid ----------------
__device__ inline unsigned int fkey(float f) {
    unsigned int u = __float_as_uint(f);
    return (u & 0x80000000u) ? ~u : (u | 0x80000000u);
}

__global__ void topk_kernel(const float* __restrict__ score,
                            float* __restrict__ out_score,
                            float* __restrict__ sig) {
    __shared__ float s[T];
    __shared__ unsigned int hist[2048];
    __shared__ int partial[256];
    __shared__ unsigned int sh_bin;
    __shared__ int sh_need;
    int b = blockIdx.x;
    int tid = threadIdx.x;
    for (int t = tid; t < T; t += 256) s[t] = score[b*T + t];
    __syncthreads();

    int need = KTOP;
    unsigned int b1 = 0, b2 = 0, b3 = 0;
    for (int pass = 0; pass < 3; ++pass) {
        for (int i = tid; i < 2048; i += 256) hist[i] = 0u;
        __syncthreads();
        for (int t = tid; t < T; t += 256) {
            unsigned int k = fkey(s[t]);
            if (pass == 0) {
                atomicAdd(&hist[k >> 21], 1u);
            } else if (pass == 1) {
                if ((k >> 21) == b1) atomicAdd(&hist[(k >> 10) & 0x7FFu], 1u);
            } else {
                if ((k >> 10) == ((b1 << 11) | b2)) atomicAdd(&hist[k & 0x3FFu], 1u);
            }
        }
        __syncthreads();
        { unsigned int a = 0;
          for (int i = 0; i < 8; ++i) a += hist[tid*8 + i];
          partial[tid] = (int)a; }
        __syncthreads();
        if (tid == 0) {
            int cum = 0, bsel = 0;
            for (int g = 255; g >= 0; --g) {
                if (cum + partial[g] >= need) {
                    for (int bb = g*8 + 7; ; --bb) {
                        if (cum + (int)hist[bb] >= need) { bsel = bb; break; }
                        cum += (int)hist[bb];
                    }
                    sh_bin = (unsigned int)bsel; sh_need = need - cum;
                    break;
                }
                cum += partial[g];
            }
        }
        __syncthreads();
        if (pass == 0) b1 = sh_bin;
        else if (pass == 1) b2 = sh_bin;
        else b3 = sh_bin;
        need = sh_need;
        __syncthreads();
    }
    unsigned int vstar = (b1 << 21) | (b2 << 10) | b3;
    int nt = need;   // #ties at vstar to keep (lowest indices first, = lax.top_k stability)

    for (int t = tid; t < T; t += 256) {
        float v = s[t];
        unsigned int k = fkey(v);
        bool keep = (k > vstar);
        if (k == vstar) {
            int rank = 0;
            for (int q = 0; q < t; ++q) if (fkey(s[q]) == vstar) ++rank;
            keep = (rank < nt);
        }
        float m = keep ? v : 0.f;
        out_score[b*T + t] = m;
        sig[b*T + t] = 1.f / (1.f + expf(-m));
    }
}

// ---------------- den[t] = sum_b sig[b][t] ----------------
__global__ void den_kernel(const float* __restrict__ sig, float* __restrict__ den) {
    int t = blockIdx.x*256 + threadIdx.x;
    if (t < T) {
        float a = 0.f;
        for (int b = 0; b < B; ++b) a += sig[b*T + t];
        den[t] = a;
    }
}

// ---------------- aw[b][t] = sig/den ----------------
__global__ void aw_kernel(const float* __restrict__ sig, const float* __restrict__ den,
                          float* __restrict__ aw) {
    int t = blockIdx.x*256 + threadIdx.x;
    int b = blockIdx.y;
    if (t < T) aw[b*T + t] = sig[b*T + t] / den[t];
}

// ---------------- context partials over t-chunks ----------------
__global__ void ctx_kernel(const float* __restrict__ values, const float* __restrict__ sig,
                           const float* __restrict__ den, float* __restrict__ part) {
    int tc = blockIdx.x, b = blockIdx.y, h = threadIdx.x;
    int tbeg = tc*250, tend = min(T, tbeg + 250);
    float acc = 0.f;
    for (int t = tbeg; t < tend; ++t) {
        float a = sig[b*T + t] / den[t];
        acc += a * values[((long)b*T + t)*H + h];
    }
    part[(tc*B + b)*H + h] = acc;
}

__global__ void ctx_reduce(const float* __restrict__ part, float* __restrict__ out0) {
    int b = blockIdx.x, h = threadIdx.x;
    float a = 0.f;
    #pragma unroll
    for (int c = 0; c < 8; ++c) a += part[(c*B + b)*H + h];
    out0[b*H + h] = a;
}

// ---------------- launcher ----------------
extern "C" void kernel_launch(void* const* d_in, const int* in_sizes, int n_in,
                              void* d_out, int out_size, void* d_ws, size_t ws_size,
                              hipStream_t stream) {
    (void)in_sizes; (void)n_in; (void)out_size; (void)ws_size;
    const float* query  = (const float*)d_in[0];
    const float* values = (const float*)d_in[1];
    const float* prev   = (const float*)d_in[2];
    const float* W1w    = (const float*)d_in[3];
    const float* W1b    = (const float*)d_in[4];
    const float* W2w    = (const float*)d_in[5];
    const float* W2b    = (const float*)d_in[6];
    const float* Vw     = (const float*)d_in[7];
    const float* Vb     = (const float*)d_in[8];
    const float* convw  = (const float*)d_in[9];
    const float* lp     = (const float*)d_in[10];

    float* ws = (float*)d_ws;
    float* out0 = (float*)d_out;            // context [B,H]
    float* out1 = out0 + B*H;               // attention_weights [B,T]
    float* out2 = out1 + BT;                // masked score [B,T]

    qproj_kernel<<<dim3(B), 256, 0, stream>>>(query, W2w, W2b, ws + WS_QPROJ);
    conv_kernel<<<dim3(63, 4), 256, 0, stream>>>(prev, convw, ws + WS_CONVPART);
    conv_reduce<<<dim3(999), 256, 0, stream>>>(ws + WS_CONVPART, ws + WS_CONVO);
    score_kernel<<<dim3(32, B), 256, 0, stream>>>(values, W1w, W1b, Vw, Vb, lp,
                                                  ws + WS_QPROJ, ws + WS_CONVO,
                                                  ws + WS_SCORE);
    topk_kernel<<<dim3(B), 256, 0, stream>>>(ws + WS_SCORE, out2, ws + WS_SIG);
    den_kernel<<<dim3(8), 256, 0, stream>>>(ws + WS_SIG, ws + WS_DEN);
    aw_kernel<<<dim3(8, B), 256, 0, stream>>>(ws + WS_SIG, ws + WS_DEN, out1);
    ctx_kernel<<<dim3(8, B), 256, 0, stream>>>(values, ws + WS_SIG, ws + WS_DEN,
                                               ws + WS_CTXPART);
    ctx_reduce<<<dim3(B), 256, 0, stream>>>(ws + WS_CTXPART, out0);
}

// Round 2
// 3891.898 us; speedup vs baseline: 2.4748x; 2.4748x over previous
//
#include <hip/hip_runtime.h>
#include <math.h>

#define B 128
#define T 1998
#define H 256
#define U 256
#define KTOP 1332
#define BT (B*T)

// ---------------- workspace layout (float elements) ----------------
#define WS_CONVPART 0
#define WS_SCORE    0
#define WS_SIG      (BT)
#define WS_DEN      (2*BT)
#define WS_CTXPART  (2*BT + 2048)
#define WS_CONVO    (4*BT)
#define WS_QPROJ    (5*BT)

// ---------------- q_proj = query @ W2^T + b2 ----------------
__global__ void qproj_kernel(const float* __restrict__ query,
                             const float* __restrict__ W2w,
                             const float* __restrict__ W2b,
                             float* __restrict__ qproj) {
    __shared__ __align__(16) float qs[H];
    int b = blockIdx.x;
    int u = threadIdx.x;
    qs[u] = query[b*H + u];
    __syncthreads();
    const float4* w  = (const float4*)(W2w + u*H);
    const float4* q4 = (const float4*)qs;
    float acc = 0.f;
    #pragma unroll 8
    for (int i = 0; i < H/4; ++i) {
        float4 wv = w[i]; float4 qv = q4[i];
        acc += wv.x*qv.x + wv.y*qv.y + wv.z*qv.z + wv.w*qv.w;
    }
    qproj[b*U + u] = acc + W2b[u];
}

// ---------------- conv: part[c][b][t] = sum_{i in chunk c} prev[b,i]*conv_w[t,i,3] ----------------
#define CT 32
#define CCHUNK 500
__global__ __launch_bounds__(256)
void conv_kernel(const float* __restrict__ prev,
                 const float* __restrict__ convw,
                 float* __restrict__ part) {
    __shared__ __align__(16) float W3s[CT*68];   // pad 68: odd #16B-groups per row
    __shared__ __align__(16) float Ps[B*68];
    int t0 = blockIdx.x * CT;
    int i_begin = blockIdx.y * CCHUNK;
    int i_end = min(T, i_begin + CCHUNK);
    int tid = threadIdx.x;
    int tx = tid & 7;          // -> t = t0 + tx + 8r
    int ty = tid >> 3;         // -> b = ty + 32j
    float acc[4][4] = {};
    for (int i0 = i_begin; i0 < i_end; i0 += 64) {
        int ni = i_end - i0; if (ni > 64) ni = 64;
        #pragma unroll
        for (int r = 0; r < 8; ++r) {              // stage W3 32x64 (strided x7 gather)
            int idx = tid + 256*r;
            int tl = idx >> 6, il = idx & 63;
            int t = t0 + tl;
            float v = 0.f;
            if (il < ni && t < T) v = convw[((long)t*T + (i0+il))*7 + 3];
            W3s[tl*68 + il] = v;
        }
        #pragma unroll
        for (int r = 0; r < 16; ++r) {             // stage P 128x64 via float2
            int idx = tid + 256*r;
            int bl = idx >> 5, i2 = idx & 31;
            int il = i2*2;
            float vx = 0.f, vy = 0.f;
            if (il < ni) {
                if (il + 1 < ni) {
                    float2 v = *(const float2*)(prev + bl*T + i0 + il);
                    vx = v.x; vy = v.y;
                } else vx = prev[bl*T + i0 + il];
            }
            Ps[bl*68 + il] = vx; Ps[bl*68 + il + 1] = vy;
        }
        __syncthreads();
        const float4* W3f = (const float4*)W3s;
        const float4* Pf  = (const float4*)Ps;
        #pragma unroll
        for (int i4 = 0; i4 < 16; ++i4) {
            float4 w4[4], p4[4];
            #pragma unroll
            for (int r = 0; r < 4; ++r) w4[r] = W3f[(tx + 8*r)*17 + i4];
            #pragma unroll
            for (int j = 0; j < 4; ++j) p4[j] = Pf[(ty + 32*j)*17 + i4];
            #pragma unroll
            for (int r = 0; r < 4; ++r)
                #pragma unroll
                for (int j = 0; j < 4; ++j)
                    acc[r][j] += w4[r].x*p4[j].x + w4[r].y*p4[j].y
                               + w4[r].z*p4[j].z + w4[r].w*p4[j].w;
        }
        __syncthreads();
    }
    int cb = blockIdx.y;
    #pragma unroll
    for (int r = 0; r < 4; ++r) {
        int t = t0 + tx + 8*r;
        if (t < T)
            #pragma unroll
            for (int j = 0; j < 4; ++j)
                part[cb*BT + (ty + 32*j)*T + t] = acc[r][j];
    }
}

__global__ void conv_reduce(const float* __restrict__ part, float* __restrict__ convo) {
    int i = blockIdx.x*256 + threadIdx.x;
    if (i < BT) convo[i] = (part[i] + part[BT+i]) + (part[2*BT+i] + part[3*BT+i]);
}

// ---------------- fused score: V.tanh(values@W1^T + b1 + qproj + convo*lp) + Vb ----------------
// R2: __launch_bounds__(256) WITHOUT min-waves arg. (256,2) capped VGPR at 128
// and spilled acc[4][16] to scratch -> 29 GB of scratch traffic, 9 ms.
__global__ __launch_bounds__(256)
void score_kernel(const float* __restrict__ values, const float* __restrict__ W1w,
                  const float* __restrict__ W1b, const float* __restrict__ Vw,
                  const float* __restrict__ Vb, const float* __restrict__ lp,
                  const float* __restrict__ qproj, const float* __restrict__ convo,
                  float* __restrict__ score) {
    __shared__ __align__(16) float Vs[64*36];     // stride 36: 9 (odd) 16B-groups/row
    __shared__ __align__(16) float W1s[256*36];
    __shared__ float qpS[U], bS[U], vwS[U], lpS[U];
    int b  = blockIdx.y;
    int t0 = blockIdx.x * 64;
    int tid = threadIdx.x;
    int tx = tid & 15;         // -> u = tx + 16j
    int ty = tid >> 4;         // -> t_local = ty + 16r
    qpS[tid] = qproj[b*U + tid];
    bS[tid]  = W1b[tid];
    vwS[tid] = Vw[tid];
    lpS[tid] = lp[tid];
    float acc[4][16] = {};
    const float4* Vsf = (const float4*)Vs;
    const float4* Wsf = (const float4*)W1s;
    for (int k0 = 0; k0 < H; k0 += 32) {
        __syncthreads();
        #pragma unroll
        for (int r = 0; r < 8; ++r) {              // stage W1 256x32
            int idx = tid + 256*r;
            int u = idx >> 3, f4 = idx & 7;
            float4 v = *(const float4*)(W1w + u*H + k0 + f4*4);
            *(float4*)(W1s + u*36 + f4*4) = v;
        }
        #pragma unroll
        for (int r = 0; r < 2; ++r) {              // stage values 64x32
            int idx = tid + 256*r;
            int row = idx >> 3, f4 = idx & 7;
            int t = t0 + row;
            float4 v = make_float4(0.f,0.f,0.f,0.f);
            if (t < T) v = *(const float4*)(values + ((long)b*T + t)*H + k0 + f4*4);
            *(float4*)(Vs + row*36 + f4*4) = v;
        }
        __syncthreads();
        #pragma unroll
        for (int k4 = 0; k4 < 8; ++k4) {
            float4 v4[4];
            #pragma unroll
            for (int r = 0; r < 4; ++r) v4[r] = Vsf[(ty + 16*r)*9 + k4];
            #pragma unroll
            for (int j = 0; j < 16; ++j) {
                float4 w4 = Wsf[(tx + 16*j)*9 + k4];
                #pragma unroll
                for (int r = 0; r < 4; ++r)
                    acc[r][j] += v4[r].x*w4.x + v4[r].y*w4.y + v4[r].z*w4.z + v4[r].w*w4.w;
            }
        }
    }
    float vb = Vb[0];
    #pragma unroll
    for (int r = 0; r < 4; ++r) {
        int t = t0 + ty + 16*r;
        float c = (t < T) ? convo[b*T + t] : 0.f;
        float part = 0.f;
        #pragma unroll
        for (int j = 0; j < 16; ++j) {
            int u = tx + 16*j;
            float s = acc[r][j] + bS[u] + qpS[u] + c*lpS[u];
            part += vwS[u] * tanhf(s);
        }
        part += __shfl_xor(part, 1);
        part += __shfl_xor(part, 2);
        part += __shfl_xor(part, 4);
        part += __shfl_xor(part, 8);
        if (tx == 0 && t < T) score[b*T + t] = part + vb;
    }
}

// ---------------- per-row exact top-K mask (radix select 11/11/10) + sigmoid ----------------
__device__ inline unsigned int fkey(float f) {
    unsigned int u = __float_as_uint(f);
    return (u & 0x80000000u) ? ~u : (u | 0x80000000u);
}

__global__ void topk_kernel(const float* __restrict__ score,
                            float* __restrict__ out_score,
                            float* __restrict__ sig) {
    __shared__ float s[T];
    __shared__ unsigned int hist[2048];
    __shared__ int partial[256];
    __shared__ unsigned int sh_bin;
    __shared__ int sh_need;
    int b = blockIdx.x;
    int tid = threadIdx.x;
    for (int t = tid; t < T; t += 256) s[t] = score[b*T + t];
    __syncthreads();

    int need = KTOP;
    unsigned int b1 = 0, b2 = 0, b3 = 0;
    for (int pass = 0; pass < 3; ++pass) {
        for (int i = tid; i < 2048; i += 256) hist[i] = 0u;
        __syncthreads();
        for (int t = tid; t < T; t += 256) {
            unsigned int k = fkey(s[t]);
            if (pass == 0) {
                atomicAdd(&hist[k >> 21], 1u);
            } else if (pass == 1) {
                if ((k >> 21) == b1) atomicAdd(&hist[(k >> 10) & 0x7FFu], 1u);
            } else {
                if ((k >> 10) == ((b1 << 11) | b2)) atomicAdd(&hist[k & 0x3FFu], 1u);
            }
        }
        __syncthreads();
        { unsigned int a = 0;
          for (int i = 0; i < 8; ++i) a += hist[tid*8 + i];
          partial[tid] = (int)a; }
        __syncthreads();
        if (tid == 0) {
            int cum = 0, bsel = 0;
            for (int g = 255; g >= 0; --g) {
                if (cum + partial[g] >= need) {
                    for (int bb = g*8 + 7; ; --bb) {
                        if (cum + (int)hist[bb] >= need) { bsel = bb; break; }
                        cum += (int)hist[bb];
                    }
                    sh_bin = (unsigned int)bsel; sh_need = need - cum;
                    break;
                }
                cum += partial[g];
            }
        }
        __syncthreads();
        if (pass == 0) b1 = sh_bin;
        else if (pass == 1) b2 = sh_bin;
        else b3 = sh_bin;
        need = sh_need;
        __syncthreads();
    }
    unsigned int vstar = (b1 << 21) | (b2 << 10) | b3;
    int nt = need;   // #ties at vstar to keep (lowest indices first)

    for (int t = tid; t < T; t += 256) {
        float v = s[t];
        unsigned int k = fkey(v);
        bool keep = (k > vstar);
        if (k == vstar) {
            int rank = 0;
            for (int q = 0; q < t; ++q) if (fkey(s[q]) == vstar) ++rank;
            keep = (rank < nt);
        }
        float m = keep ? v : 0.f;
        out_score[b*T + t] = m;
        sig[b*T + t] = 1.f / (1.f + expf(-m));
    }
}

// ---------------- den[t] = sum_b sig[b][t] ----------------
__global__ void den_kernel(const float* __restrict__ sig, float* __restrict__ den) {
    int t = blockIdx.x*256 + threadIdx.x;
    if (t < T) {
        float a = 0.f;
        for (int b = 0; b < B; ++b) a += sig[b*T + t];
        den[t] = a;
    }
}

// ---------------- aw[b][t] = sig/den ----------------
__global__ void aw_kernel(const float* __restrict__ sig, const float* __restrict__ den,
                          float* __restrict__ aw) {
    int t = blockIdx.x*256 + threadIdx.x;
    int b = blockIdx.y;
    if (t < T) aw[b*T + t] = sig[b*T + t] / den[t];
}

// ---------------- context partials over t-chunks ----------------
__global__ void ctx_kernel(const float* __restrict__ values, const float* __restrict__ sig,
                           const float* __restrict__ den, float* __restrict__ part) {
    int tc = blockIdx.x, b = blockIdx.y, h = threadIdx.x;
    int tbeg = tc*250, tend = min(T, tbeg + 250);
    float acc = 0.f;
    for (int t = tbeg; t < tend; ++t) {
        float a = sig[b*T + t] / den[t];
        acc += a * values[((long)b*T + t)*H + h];
    }
    part[(tc*B + b)*H + h] = acc;
}

__global__ void ctx_reduce(const float* __restrict__ part, float* __restrict__ out0) {
    int b = blockIdx.x, h = threadIdx.x;
    float a = 0.f;
    #pragma unroll
    for (int c = 0; c < 8; ++c) a += part[(c*B + b)*H + h];
    out0[b*H + h] = a;
}

// ---------------- launcher ----------------
extern "C" void kernel_launch(void* const* d_in, const int* in_sizes, int n_in,
                              void* d_out, int out_size, void* d_ws, size_t ws_size,
                              hipStream_t stream) {
    (void)in_sizes; (void)n_in; (void)out_size; (void)ws_size;
    const float* query  = (const float*)d_in[0];
    const float* values = (const float*)d_in[1];
    const float* prev   = (const float*)d_in[2];
    const float* W1w    = (const float*)d_in[3];
    const float* W1b    = (const float*)d_in[4];
    const float* W2w    = (const float*)d_in[5];
    const float* W2b    = (const float*)d_in[6];
    const float* Vw     = (const float*)d_in[7];
    const float* Vb     = (const float*)d_in[8];
    const float* convw  = (const float*)d_in[9];
    const float* lp     = (const float*)d_in[10];

    float* ws = (float*)d_ws;
    float* out0 = (float*)d_out;            // context [B,H]
    float* out1 = out0 + B*H;               // attention_weights [B,T]
    float* out2 = out1 + BT;                // masked score [B,T]

    qproj_kernel<<<dim3(B), 256, 0, stream>>>(query, W2w, W2b, ws + WS_QPROJ);
    conv_kernel<<<dim3(63, 4), 256, 0, stream>>>(prev, convw, ws + WS_CONVPART);
    conv_reduce<<<dim3(999), 256, 0, stream>>>(ws + WS_CONVPART, ws + WS_CONVO);
    score_kernel<<<dim3(32, B), 256, 0, stream>>>(values, W1w, W1b, Vw, Vb, lp,
                                                  ws + WS_QPROJ, ws + WS_CONVO,
                                                  ws + WS_SCORE);
    topk_kernel<<<dim3(B), 256, 0, stream>>>(ws + WS_SCORE, out2, ws + WS_SIG);
    den_kernel<<<dim3(8), 256, 0, stream>>>(ws + WS_SIG, ws + WS_DEN);
    aw_kernel<<<dim3(8, B), 256, 0, stream>>>(ws + WS_SIG, ws + WS_DEN, out1);
    ctx_kernel<<<dim3(8, B), 256, 0, stream>>>(values, ws + WS_SIG, ws + WS_DEN,
                                               ws + WS_CTXPART);
    ctx_reduce<<<dim3(B), 256, 0, stream>>>(ws + WS_CTXPART, out0);
}

// Round 3
// 1968.411 us; speedup vs baseline: 4.8930x; 1.9772x over previous
//
#include <hip/hip_runtime.h>
#include <math.h>

#define B 128
#define T 1998
#define H 256
#define U 256
#define KTOP 1332
#define BT (B*T)

// ---------------- workspace layout (float elements) ----------------
// phase 1 (conv): partials [4][B][T] at 0..4BT, convo at 4BT
// phase 2 (score): spart[2][B][T] at 0..2BT (overwrites conv partials - OK, consumed),
//                  sig at 2BT, den at 3BT, ctxpart at 3BT+2048 (overlaps convo region -
//                  OK, convo consumed by score before ctx runs)
#define WS_CONVPART 0
#define WS_SPART    0
#define WS_SIG      (2*BT)
#define WS_DEN      (3*BT)
#define WS_CTXPART  (3*BT + 2048)
#define WS_CONVO    (4*BT)
#define WS_QPROJ    (5*BT)

// ---------------- q_proj = query @ W2^T + b2 ----------------
__global__ void qproj_kernel(const float* __restrict__ query,
                             const float* __restrict__ W2w,
                             const float* __restrict__ W2b,
                             float* __restrict__ qproj) {
    __shared__ __align__(16) float qs[H];
    int b = blockIdx.x;
    int u = threadIdx.x;
    qs[u] = query[b*H + u];
    __syncthreads();
    const float4* w  = (const float4*)(W2w + u*H);
    const float4* q4 = (const float4*)qs;
    float acc = 0.f;
    #pragma unroll 8
    for (int i = 0; i < H/4; ++i) {
        float4 wv = w[i]; float4 qv = q4[i];
        acc += wv.x*qv.x + wv.y*qv.y + wv.z*qv.z + wv.w*qv.w;
    }
    qproj[b*U + u] = acc + W2b[u];
}

// ---------------- conv: part[c][b][t] = sum_{i in chunk c} prev[b,i]*conv_w[t,i,3] ----------------
#define CT 32
#define CCHUNK 500
__global__ __launch_bounds__(256)
void conv_kernel(const float* __restrict__ prev,
                 const float* __restrict__ convw,
                 float* __restrict__ part) {
    __shared__ __align__(16) float W3s[CT*68];
    __shared__ __align__(16) float Ps[B*68];
    int t0 = blockIdx.x * CT;
    int i_begin = blockIdx.y * CCHUNK;
    int i_end = min(T, i_begin + CCHUNK);
    int tid = threadIdx.x;
    int tx = tid & 7;
    int ty = tid >> 3;
    float acc[4][4] = {};
    for (int i0 = i_begin; i0 < i_end; i0 += 64) {
        int ni = i_end - i0; if (ni > 64) ni = 64;
        #pragma unroll
        for (int r = 0; r < 8; ++r) {
            int idx = tid + 256*r;
            int tl = idx >> 6, il = idx & 63;
            int t = t0 + tl;
            float v = 0.f;
            if (il < ni && t < T) v = convw[((long)t*T + (i0+il))*7 + 3];
            W3s[tl*68 + il] = v;
        }
        #pragma unroll
        for (int r = 0; r < 16; ++r) {
            int idx = tid + 256*r;
            int bl = idx >> 5, i2 = idx & 31;
            int il = i2*2;
            float vx = 0.f, vy = 0.f;
            if (il < ni) {
                if (il + 1 < ni) {
                    float2 v = *(const float2*)(prev + bl*T + i0 + il);
                    vx = v.x; vy = v.y;
                } else vx = prev[bl*T + i0 + il];
            }
            Ps[bl*68 + il] = vx; Ps[bl*68 + il + 1] = vy;
        }
        __syncthreads();
        const float4* W3f = (const float4*)W3s;
        const float4* Pf  = (const float4*)Ps;
        #pragma unroll
        for (int i4 = 0; i4 < 16; ++i4) {
            float4 w4[4], p4[4];
            #pragma unroll
            for (int r = 0; r < 4; ++r) w4[r] = W3f[(tx + 8*r)*17 + i4];
            #pragma unroll
            for (int j = 0; j < 4; ++j) p4[j] = Pf[(ty + 32*j)*17 + i4];
            #pragma unroll
            for (int r = 0; r < 4; ++r)
                #pragma unroll
                for (int j = 0; j < 4; ++j)
                    acc[r][j] += w4[r].x*p4[j].x + w4[r].y*p4[j].y
                               + w4[r].z*p4[j].z + w4[r].w*p4[j].w;
        }
        __syncthreads();
    }
    int cb = blockIdx.y;
    #pragma unroll
    for (int r = 0; r < 4; ++r) {
        int t = t0 + tx + 8*r;
        if (t < T)
            #pragma unroll
            for (int j = 0; j < 4; ++j)
                part[cb*BT + (ty + 32*j)*T + t] = acc[r][j];
    }
}

__global__ void conv_reduce(const float* __restrict__ part, float* __restrict__ convo) {
    int i = blockIdx.x*256 + threadIdx.x;
    if (i < BT) convo[i] = (part[i] + part[BT+i]) + (part[2*BT+i] + part[3*BT+i]);
}

// ---------------- fused partial score over a 128-u split ----------------
// R3: U-split (tanh is element-wise in u, so score = sum of two u-halves).
// Per-thread accs 64 -> 32; demand fits under 256 VGPRs -> no scratch spill
// (R1: (256,2) cap spilled 29 GB; R2: demand >256 still spilled 7 GB).
__global__ __launch_bounds__(256)
void score_kernel(const float* __restrict__ values, const float* __restrict__ W1w,
                  const float* __restrict__ W1b, const float* __restrict__ Vw,
                  const float* __restrict__ lp,
                  const float* __restrict__ qproj, const float* __restrict__ convo,
                  float* __restrict__ spart) {
    __shared__ __align__(16) float Vs[64*36];      // 64 t x 32 k, stride 36
    __shared__ __align__(16) float W1s[128*36];    // 128 u x 32 k, stride 36
    __shared__ float qpS[128], bS[128], vwS[128], lpS[128];
    int b  = blockIdx.z;
    int u0 = blockIdx.y * 128;
    int t0 = blockIdx.x * 64;
    int tid = threadIdx.x;
    int tx = tid & 15;         // u = u0 + tx + 16j, j<8
    int ty = tid >> 4;         // t = t0 + ty + 16r, r<4
    if (tid < 128) {
        int u = u0 + tid;
        qpS[tid] = qproj[b*U + u];
        bS[tid]  = W1b[u];
        vwS[tid] = Vw[u];
        lpS[tid] = lp[u];
    }
    float acc[4][8] = {};
    const float4* Vsf = (const float4*)Vs;
    const float4* Wsf = (const float4*)W1s;
    for (int k0 = 0; k0 < H; k0 += 32) {
        __syncthreads();
        #pragma unroll
        for (int r = 0; r < 4; ++r) {              // stage W1 128x32
            int idx = tid + 256*r;
            int u = idx >> 3, f4 = idx & 7;
            float4 v = *(const float4*)(W1w + (u0 + u)*H + k0 + f4*4);
            *(float4*)(W1s + u*36 + f4*4) = v;
        }
        #pragma unroll
        for (int r = 0; r < 2; ++r) {              // stage values 64x32
            int idx = tid + 256*r;
            int row = idx >> 3, f4 = idx & 7;
            int t = t0 + row;
            float4 v = make_float4(0.f,0.f,0.f,0.f);
            if (t < T) v = *(const float4*)(values + ((long)b*T + t)*H + k0 + f4*4);
            *(float4*)(Vs + row*36 + f4*4) = v;
        }
        __syncthreads();
        #pragma unroll
        for (int k4 = 0; k4 < 8; ++k4) {
            float4 v4[4];
            #pragma unroll
            for (int r = 0; r < 4; ++r) v4[r] = Vsf[(ty + 16*r)*9 + k4];
            #pragma unroll
            for (int j = 0; j < 8; ++j) {
                float4 w4 = Wsf[(tx + 16*j)*9 + k4];
                #pragma unroll
                for (int r = 0; r < 4; ++r)
                    acc[r][j] += v4[r].x*w4.x + v4[r].y*w4.y + v4[r].z*w4.z + v4[r].w*w4.w;
            }
        }
    }
    #pragma unroll
    for (int r = 0; r < 4; ++r) {
        int t = t0 + ty + 16*r;
        float c = (t < T) ? convo[b*T + t] : 0.f;
        float part = 0.f;
        #pragma unroll
        for (int j = 0; j < 8; ++j) {
            int ul = tx + 16*j;
            float s = acc[r][j] + bS[ul] + qpS[ul] + c*lpS[ul];
            part += vwS[ul] * tanhf(s);
        }
        part += __shfl_xor(part, 1);
        part += __shfl_xor(part, 2);
        part += __shfl_xor(part, 4);
        part += __shfl_xor(part, 8);
        if (tx == 0 && t < T) spart[blockIdx.y*BT + b*T + t] = part;
    }
}

// ---------------- per-row exact top-K mask (radix select 11/11/10) + sigmoid ----------------
__device__ inline unsigned int fkey(float f) {
    unsigned int u = __float_as_uint(f);
    return (u & 0x80000000u) ? ~u : (u | 0x80000000u);
}

__global__ void topk_kernel(const float* __restrict__ spart,
                            const float* __restrict__ Vb,
                            float* __restrict__ out_score,
                            float* __restrict__ sig) {
    __shared__ float s[T];
    __shared__ unsigned int hist[2048];
    __shared__ int partial[256];
    __shared__ unsigned int sh_bin;
    __shared__ int sh_need;
    int b = blockIdx.x;
    int tid = threadIdx.x;
    float vb = Vb[0];
    for (int t = tid; t < T; t += 256)
        s[t] = spart[b*T + t] + spart[BT + b*T + t] + vb;
    __syncthreads();

    int need = KTOP;
    unsigned int b1 = 0, b2 = 0, b3 = 0;
    for (int pass = 0; pass < 3; ++pass) {
        for (int i = tid; i < 2048; i += 256) hist[i] = 0u;
        __syncthreads();
        for (int t = tid; t < T; t += 256) {
            unsigned int k = fkey(s[t]);
            if (pass == 0) {
                atomicAdd(&hist[k >> 21], 1u);
            } else if (pass == 1) {
                if ((k >> 21) == b1) atomicAdd(&hist[(k >> 10) & 0x7FFu], 1u);
            } else {
                if ((k >> 10) == ((b1 << 11) | b2)) atomicAdd(&hist[k & 0x3FFu], 1u);
            }
        }
        __syncthreads();
        { unsigned int a = 0;
          for (int i = 0; i < 8; ++i) a += hist[tid*8 + i];
          partial[tid] = (int)a; }
        __syncthreads();
        if (tid == 0) {
            int cum = 0, bsel = 0;
            for (int g = 255; g >= 0; --g) {
                if (cum + partial[g] >= need) {
                    for (int bb = g*8 + 7; ; --bb) {
                        if (cum + (int)hist[bb] >= need) { bsel = bb; break; }
                        cum += (int)hist[bb];
                    }
                    sh_bin = (unsigned int)bsel; sh_need = need - cum;
                    break;
                }
                cum += partial[g];
            }
        }
        __syncthreads();
        if (pass == 0) b1 = sh_bin;
        else if (pass == 1) b2 = sh_bin;
        else b3 = sh_bin;
        need = sh_need;
        __syncthreads();
    }
    unsigned int vstar = (b1 << 21) | (b2 << 10) | b3;
    int nt = need;   // #ties at vstar to keep (lowest indices first)

    for (int t = tid; t < T; t += 256) {
        float v = s[t];
        unsigned int k = fkey(v);
        bool keep = (k > vstar);
        if (k == vstar) {
            int rank = 0;
            for (int q = 0; q < t; ++q) if (fkey(s[q]) == vstar) ++rank;
            keep = (rank < nt);
        }
        float m = keep ? v : 0.f;
        out_score[b*T + t] = m;
        sig[b*T + t] = 1.f / (1.f + expf(-m));
    }
}

// ---------------- den[t] = sum_b sig[b][t] ----------------
__global__ void den_kernel(const float* __restrict__ sig, float* __restrict__ den) {
    int t = blockIdx.x*256 + threadIdx.x;
    if (t < T) {
        float a = 0.f;
        for (int b = 0; b < B; ++b) a += sig[b*T + t];
        den[t] = a;
    }
}

// ---------------- aw[b][t] = sig/den ----------------
__global__ void aw_kernel(const float* __restrict__ sig, const float* __restrict__ den,
                          float* __restrict__ aw) {
    int t = blockIdx.x*256 + threadIdx.x;
    int b = blockIdx.y;
    if (t < T) aw[b*T + t] = sig[b*T + t] / den[t];
}

// ---------------- context partials over t-chunks ----------------
__global__ void ctx_kernel(const float* __restrict__ values, const float* __restrict__ sig,
                           const float* __restrict__ den, float* __restrict__ part) {
    int tc = blockIdx.x, b = blockIdx.y, h = threadIdx.x;
    int tbeg = tc*250, tend = min(T, tbeg + 250);
    float acc = 0.f;
    for (int t = tbeg; t < tend; ++t) {
        float a = sig[b*T + t] / den[t];
        acc += a * values[((long)b*T + t)*H + h];
    }
    part[(tc*B + b)*H + h] = acc;
}

__global__ void ctx_reduce(const float* __restrict__ part, float* __restrict__ out0) {
    int b = blockIdx.x, h = threadIdx.x;
    float a = 0.f;
    #pragma unroll
    for (int c = 0; c < 8; ++c) a += part[(c*B + b)*H + h];
    out0[b*H + h] = a;
}

// ---------------- launcher ----------------
extern "C" void kernel_launch(void* const* d_in, const int* in_sizes, int n_in,
                              void* d_out, int out_size, void* d_ws, size_t ws_size,
                              hipStream_t stream) {
    (void)in_sizes; (void)n_in; (void)out_size; (void)ws_size;
    const float* query  = (const float*)d_in[0];
    const float* values = (const float*)d_in[1];
    const float* prev   = (const float*)d_in[2];
    const float* W1w    = (const float*)d_in[3];
    const float* W1b    = (const float*)d_in[4];
    const float* W2w    = (const float*)d_in[5];
    const float* W2b    = (const float*)d_in[6];
    const float* Vw     = (const float*)d_in[7];
    const float* Vb     = (const float*)d_in[8];
    const float* convw  = (const float*)d_in[9];
    const float* lp     = (const float*)d_in[10];

    float* ws = (float*)d_ws;
    float* out0 = (float*)d_out;            // context [B,H]
    float* out1 = out0 + B*H;               // attention_weights [B,T]
    float* out2 = out1 + BT;                // masked score [B,T]

    qproj_kernel<<<dim3(B), 256, 0, stream>>>(query, W2w, W2b, ws + WS_QPROJ);
    conv_kernel<<<dim3(63, 4), 256, 0, stream>>>(prev, convw, ws + WS_CONVPART);
    conv_reduce<<<dim3(999), 256, 0, stream>>>(ws + WS_CONVPART, ws + WS_CONVO);
    score_kernel<<<dim3(32, 2, B), 256, 0, stream>>>(values, W1w, W1b, Vw, lp,
                                                     ws + WS_QPROJ, ws + WS_CONVO,
                                                     ws + WS_SPART);
    topk_kernel<<<dim3(B), 256, 0, stream>>>(ws + WS_SPART, Vb, out2, ws + WS_SIG);
    den_kernel<<<dim3(8), 256, 0, stream>>>(ws + WS_SIG, ws + WS_DEN);
    aw_kernel<<<dim3(8, B), 256, 0, stream>>>(ws + WS_SIG, ws + WS_DEN, out1);
    ctx_kernel<<<dim3(8, B), 256, 0, stream>>>(values, ws + WS_SIG, ws + WS_DEN,
                                               ws + WS_CTXPART);
    ctx_reduce<<<dim3(B), 256, 0, stream>>>(ws + WS_CTXPART, out0);
}

// Round 4
// 1241.294 us; speedup vs baseline: 7.7592x; 1.5858x over previous
//
#include <hip/hip_runtime.h>
#include <math.h>

#define B 128
#define T 1998
#define H 256
#define U 256
#define KTOP 1332
#define BT (B*T)

typedef float v2f __attribute__((ext_vector_type(2)));

// ---------------- workspace layout (float elements) ----------------
// phase 1 (conv): partials [4][B][T] at 0..4BT, convo at 4BT
// phase 2 (score): spart[2][B][T] at 0..2BT, sig at 2BT, den at 3BT,
//                  ctxpart at 3BT+2048 (clobbers convo tail - convo dead by then)
#define WS_CONVPART 0
#define WS_SPART    0
#define WS_SIG      (2*BT)
#define WS_DEN      (3*BT)
#define WS_CTXPART  (3*BT + 2048)
#define WS_CONVO    (4*BT)
#define WS_QPROJ    (5*BT)

// ---------------- q_proj = query @ W2^T + b2 ----------------
__global__ void qproj_kernel(const float* __restrict__ query,
                             const float* __restrict__ W2w,
                             const float* __restrict__ W2b,
                             float* __restrict__ qproj) {
    __shared__ __align__(16) float qs[H];
    int b = blockIdx.x;
    int u = threadIdx.x;
    qs[u] = query[b*H + u];
    __syncthreads();
    const float4* w  = (const float4*)(W2w + u*H);
    const float4* q4 = (const float4*)qs;
    float acc = 0.f;
    #pragma unroll 8
    for (int i = 0; i < H/4; ++i) {
        float4 wv = w[i]; float4 qv = q4[i];
        acc = fmaf(wv.x, qv.x, acc); acc = fmaf(wv.y, qv.y, acc);
        acc = fmaf(wv.z, qv.z, acc); acc = fmaf(wv.w, qv.w, acc);
    }
    qproj[b*U + u] = acc + W2b[u];
}

// ---------------- conv: part[c][b][t] = sum_{i in chunk c} prev[b,i]*conv_w[t,i,3] ----------------
#define CT 32
#define CCHUNK 500
__global__ __launch_bounds__(256)
void conv_kernel(const float* __restrict__ prev,
                 const float* __restrict__ convw,
                 float* __restrict__ part) {
    __shared__ __align__(16) float W3s[CT*68];
    __shared__ __align__(16) float Ps[B*68];
    int t0 = blockIdx.x * CT;
    int i_begin = blockIdx.y * CCHUNK;
    int i_end = min(T, i_begin + CCHUNK);
    int tid = threadIdx.x;
    int tx = tid & 7;
    int ty = tid >> 3;
    float acc[4][4] = {};
    for (int i0 = i_begin; i0 < i_end; i0 += 64) {
        int ni = i_end - i0; if (ni > 64) ni = 64;
        #pragma unroll
        for (int r = 0; r < 8; ++r) {
            int idx = tid + 256*r;
            int tl = idx >> 6, il = idx & 63;
            int t = t0 + tl;
            float v = 0.f;
            if (il < ni && t < T) v = convw[((long)t*T + (i0+il))*7 + 3];
            W3s[tl*68 + il] = v;
        }
        #pragma unroll
        for (int r = 0; r < 16; ++r) {
            int idx = tid + 256*r;
            int bl = idx >> 5, i2 = idx & 31;
            int il = i2*2;
            float vx = 0.f, vy = 0.f;
            if (il < ni) {
                if (il + 1 < ni) {
                    float2 v = *(const float2*)(prev + bl*T + i0 + il);
                    vx = v.x; vy = v.y;
                } else vx = prev[bl*T + i0 + il];
            }
            Ps[bl*68 + il] = vx; Ps[bl*68 + il + 1] = vy;
        }
        __syncthreads();
        const float4* W3f = (const float4*)W3s;
        const float4* Pf  = (const float4*)Ps;
        #pragma unroll
        for (int i4 = 0; i4 < 16; ++i4) {
            float4 w4[4], p4[4];
            #pragma unroll
            for (int r = 0; r < 4; ++r) w4[r] = W3f[(tx + 8*r)*17 + i4];
            #pragma unroll
            for (int j = 0; j < 4; ++j) p4[j] = Pf[(ty + 32*j)*17 + i4];
            #pragma unroll
            for (int r = 0; r < 4; ++r)
                #pragma unroll
                for (int j = 0; j < 4; ++j) {
                    float a = acc[r][j];
                    a = fmaf(w4[r].x, p4[j].x, a);
                    a = fmaf(w4[r].y, p4[j].y, a);
                    a = fmaf(w4[r].z, p4[j].z, a);
                    a = fmaf(w4[r].w, p4[j].w, a);
                    acc[r][j] = a;
                }
        }
        __syncthreads();
    }
    int cb = blockIdx.y;
    #pragma unroll
    for (int r = 0; r < 4; ++r) {
        int t = t0 + tx + 8*r;
        if (t < T)
            #pragma unroll
            for (int j = 0; j < 4; ++j)
                part[cb*BT + (ty + 32*j)*T + t] = acc[r][j];
    }
}

__global__ void conv_reduce(const float* __restrict__ part, float* __restrict__ convo) {
    int i = blockIdx.x*256 + threadIdx.x;
    if (i < BT) convo[i] = (part[i] + part[BT+i]) + (part[2*BT+i] + part[3*BT+i]);
}

// ---------------- fused partial score over a 128-u split ----------------
// R4: even/odd-k float2 accumulators + __builtin_elementwise_fma ->
// v_pk_fma_f32 (157 TF packed path; plain v_fma is 78.6 TF) and guaranteed
// contraction (R3's a += x*y+z*w+... compiled to mul+add chains).
__global__ __launch_bounds__(256)
void score_kernel(const float* __restrict__ values, const float* __restrict__ W1w,
                  const float* __restrict__ W1b, const float* __restrict__ Vw,
                  const float* __restrict__ lp,
                  const float* __restrict__ qproj, const float* __restrict__ convo,
                  float* __restrict__ spart) {
    __shared__ __align__(16) float Vs[64*36];      // 64 t x 32 k, stride 36
    __shared__ __align__(16) float W1s[128*36];    // 128 u x 32 k, stride 36
    __shared__ float qpS[128], bS[128], vwS[128], lpS[128];
    int b  = blockIdx.z;
    int u0 = blockIdx.y * 128;
    int t0 = blockIdx.x * 64;
    int tid = threadIdx.x;
    int tx = tid & 15;         // u = u0 + tx + 16j, j<8
    int ty = tid >> 4;         // t = t0 + ty + 16r, r<4
    if (tid < 128) {
        int u = u0 + tid;
        qpS[tid] = qproj[b*U + u];
        bS[tid]  = W1b[u];
        vwS[tid] = Vw[u];
        lpS[tid] = lp[u];
    }
    v2f acc2[4][8];
    #pragma unroll
    for (int r = 0; r < 4; ++r)
        #pragma unroll
        for (int j = 0; j < 8; ++j) { v2f z = {0.f, 0.f}; acc2[r][j] = z; }

    const float4* Vsf = (const float4*)Vs;
    const float4* Wsf = (const float4*)W1s;
    for (int k0 = 0; k0 < H; k0 += 32) {
        __syncthreads();
        #pragma unroll
        for (int r = 0; r < 4; ++r) {              // stage W1 128x32
            int idx = tid + 256*r;
            int u = idx >> 3, f4 = idx & 7;
            float4 v = *(const float4*)(W1w + (u0 + u)*H + k0 + f4*4);
            *(float4*)(W1s + u*36 + f4*4) = v;
        }
        #pragma unroll
        for (int r = 0; r < 2; ++r) {              // stage values 64x32
            int idx = tid + 256*r;
            int row = idx >> 3, f4 = idx & 7;
            int t = t0 + row;
            float4 v = make_float4(0.f,0.f,0.f,0.f);
            if (t < T) v = *(const float4*)(values + ((long)b*T + t)*H + k0 + f4*4);
            *(float4*)(Vs + row*36 + f4*4) = v;
        }
        __syncthreads();
        #pragma unroll
        for (int k4 = 0; k4 < 8; ++k4) {
            v2f vlo[4], vhi[4];
            #pragma unroll
            for (int r = 0; r < 4; ++r) {
                float4 v4 = Vsf[(ty + 16*r)*9 + k4];
                v2f a = {v4.x, v4.y}; v2f c = {v4.z, v4.w};
                vlo[r] = a; vhi[r] = c;
            }
            #pragma unroll
            for (int j = 0; j < 8; ++j) {
                float4 w4 = Wsf[(tx + 16*j)*9 + k4];
                v2f wlo = {w4.x, w4.y};
                v2f whi = {w4.z, w4.w};
                #pragma unroll
                for (int r = 0; r < 4; ++r) {
                    acc2[r][j] = __builtin_elementwise_fma(vlo[r], wlo, acc2[r][j]);
                    acc2[r][j] = __builtin_elementwise_fma(vhi[r], whi, acc2[r][j]);
                }
            }
        }
    }
    #pragma unroll
    for (int r = 0; r < 4; ++r) {
        int t = t0 + ty + 16*r;
        float c = (t < T) ? convo[b*T + t] : 0.f;
        float part = 0.f;
        #pragma unroll
        for (int j = 0; j < 8; ++j) {
            int ul = tx + 16*j;
            float s = (acc2[r][j].x + acc2[r][j].y) + bS[ul] + qpS[ul] + c*lpS[ul];
            part += vwS[ul] * tanhf(s);
        }
        part += __shfl_xor(part, 1);
        part += __shfl_xor(part, 2);
        part += __shfl_xor(part, 4);
        part += __shfl_xor(part, 8);
        if (tx == 0 && t < T) spart[blockIdx.y*BT + b*T + t] = part;
    }
}

// ---------------- per-row exact top-K mask (radix select 11/11/10) + sigmoid ----------------
__device__ inline unsigned int fkey(float f) {
    unsigned int u = __float_as_uint(f);
    return (u & 0x80000000u) ? ~u : (u | 0x80000000u);
}

__global__ void zero_den(float* __restrict__ den) {
    int i = threadIdx.x + blockIdx.x*256;
    if (i < 2048) den[i] = 0.f;
}

__global__ void topk_kernel(const float* __restrict__ spart,
                            const float* __restrict__ Vb,
                            float* __restrict__ out_score,
                            float* __restrict__ sig,
                            float* __restrict__ den) {
    __shared__ float s[T];
    __shared__ unsigned int hist[2048];
    __shared__ int partial[256];
    __shared__ unsigned int sh_bin;
    __shared__ int sh_need;
    int b = blockIdx.x;
    int tid = threadIdx.x;
    float vb = Vb[0];
    for (int t = tid; t < T; t += 256)
        s[t] = spart[b*T + t] + spart[BT + b*T + t] + vb;
    __syncthreads();

    int need = KTOP;
    unsigned int b1 = 0, b2 = 0, b3 = 0;
    for (int pass = 0; pass < 3; ++pass) {
        for (int i = tid; i < 2048; i += 256) hist[i] = 0u;
        __syncthreads();
        for (int t = tid; t < T; t += 256) {
            unsigned int k = fkey(s[t]);
            if (pass == 0) {
                atomicAdd(&hist[k >> 21], 1u);
            } else if (pass == 1) {
                if ((k >> 21) == b1) atomicAdd(&hist[(k >> 10) & 0x7FFu], 1u);
            } else {
                if ((k >> 10) == ((b1 << 11) | b2)) atomicAdd(&hist[k & 0x3FFu], 1u);
            }
        }
        __syncthreads();
        { unsigned int a = 0;
          for (int i = 0; i < 8; ++i) a += hist[tid*8 + i];
          partial[tid] = (int)a; }
        __syncthreads();
        if (tid == 0) {
            int cum = 0, bsel = 0;
            for (int g = 255; g >= 0; --g) {
                if (cum + partial[g] >= need) {
                    for (int bb = g*8 + 7; ; --bb) {
                        if (cum + (int)hist[bb] >= need) { bsel = bb; break; }
                        cum += (int)hist[bb];
                    }
                    sh_bin = (unsigned int)bsel; sh_need = need - cum;
                    break;
                }
                cum += partial[g];
            }
        }
        __syncthreads();
        if (pass == 0) b1 = sh_bin;
        else if (pass == 1) b2 = sh_bin;
        else b3 = sh_bin;
        need = sh_need;
        __syncthreads();
    }
    unsigned int vstar = (b1 << 21) | (b2 << 10) | b3;
    int nt = need;   // #ties at vstar to keep (lowest indices first)

    for (int t = tid; t < T; t += 256) {
        float v = s[t];
        unsigned int k = fkey(v);
        bool keep = (k > vstar);
        if (k == vstar) {
            int rank = 0;
            for (int q = 0; q < t; ++q) if (fkey(s[q]) == vstar) ++rank;
            keep = (rank < nt);
        }
        float m = keep ? v : 0.f;
        out_score[b*T + t] = m;
        float sg = 1.f / (1.f + expf(-m));
        sig[b*T + t] = sg;
        atomicAdd(&den[t], sg);
    }
}

// ---------------- aw[b][t] = sig/den ----------------
__global__ void aw_kernel(const float* __restrict__ sig, const float* __restrict__ den,
                          float* __restrict__ aw) {
    int t = blockIdx.x*256 + threadIdx.x;
    int b = blockIdx.y;
    if (t < T) aw[b*T + t] = sig[b*T + t] / den[t];
}

// ---------------- context partials over t-chunks ----------------
__global__ void ctx_kernel(const float* __restrict__ values, const float* __restrict__ sig,
                           const float* __restrict__ den, float* __restrict__ part) {
    int tc = blockIdx.x, b = blockIdx.y, h = threadIdx.x;
    int tbeg = tc*250, tend = min(T, tbeg + 250);
    float acc = 0.f;
    for (int t = tbeg; t < tend; ++t) {
        float a = sig[b*T + t] / den[t];
        acc = fmaf(a, values[((long)b*T + t)*H + h], acc);
    }
    part[(tc*B + b)*H + h] = acc;
}

__global__ void ctx_reduce(const float* __restrict__ part, float* __restrict__ out0) {
    int b = blockIdx.x, h = threadIdx.x;
    float a = 0.f;
    #pragma unroll
    for (int c = 0; c < 8; ++c) a += part[(c*B + b)*H + h];
    out0[b*H + h] = a;
}

// ---------------- launcher ----------------
extern "C" void kernel_launch(void* const* d_in, const int* in_sizes, int n_in,
                              void* d_out, int out_size, void* d_ws, size_t ws_size,
                              hipStream_t stream) {
    (void)in_sizes; (void)n_in; (void)out_size; (void)ws_size;
    const float* query  = (const float*)d_in[0];
    const float* values = (const float*)d_in[1];
    const float* prev   = (const float*)d_in[2];
    const float* W1w    = (const float*)d_in[3];
    const float* W1b    = (const float*)d_in[4];
    const float* W2w    = (const float*)d_in[5];
    const float* W2b    = (const float*)d_in[6];
    const float* Vw     = (const float*)d_in[7];
    const float* Vb     = (const float*)d_in[8];
    const float* convw  = (const float*)d_in[9];
    const float* lp     = (const float*)d_in[10];

    float* ws = (float*)d_ws;
    float* out0 = (float*)d_out;            // context [B,H]
    float* out1 = out0 + B*H;               // attention_weights [B,T]
    float* out2 = out1 + BT;                // masked score [B,T]

    qproj_kernel<<<dim3(B), 256, 0, stream>>>(query, W2w, W2b, ws + WS_QPROJ);
    conv_kernel<<<dim3(63, 4), 256, 0, stream>>>(prev, convw, ws + WS_CONVPART);
    conv_reduce<<<dim3(999), 256, 0, stream>>>(ws + WS_CONVPART, ws + WS_CONVO);
    zero_den<<<dim3(8), 256, 0, stream>>>(ws + WS_DEN);
    score_kernel<<<dim3(32, 2, B), 256, 0, stream>>>(values, W1w, W1b, Vw, lp,
                                                     ws + WS_QPROJ, ws + WS_CONVO,
                                                     ws + WS_SPART);
    topk_kernel<<<dim3(B), 256, 0, stream>>>(ws + WS_SPART, Vb, out2, ws + WS_SIG,
                                             ws + WS_DEN);
    aw_kernel<<<dim3(8, B), 256, 0, stream>>>(ws + WS_SIG, ws + WS_DEN, out1);
    ctx_kernel<<<dim3(8, B), 256, 0, stream>>>(values, ws + WS_SIG, ws + WS_DEN,
                                               ws + WS_CTXPART);
    ctx_reduce<<<dim3(B), 256, 0, stream>>>(ws + WS_CTXPART, out0);
}